// Round 1
// baseline (229.532 us; speedup 1.0000x reference)
//
#include <hip/hip_runtime.h>

// FWHT over last dim 4096 of fp32 tensor, rows = total/4096.
// One wave (64 lanes) per row. Lane holds 64 values in VGPRs.
// Stage plan: bits 0-5 in registers -> LDS 64x64 transpose (pitch 68,
// conflict-free) -> bits 6-11 in registers -> scale 2^-39 -> coalesced store.
// Butterfly order matches reference (h = 1,2,...,2048) so the FP dependency
// graph is identical to the float32 reference.

constexpr int DIM = 4096;
constexpr int PITCH = 68;  // 64 + 4 pad floats; multiple of 4 keeps b128 alignment

__global__ __launch_bounds__(64) void fwht4096_kernel(const float* __restrict__ x,
                                                      float* __restrict__ y) {
    __shared__ float buf[64 * PITCH];  // 17,408 B
    const int lane = threadIdx.x;          // 0..63
    const long long row = blockIdx.x;      // one row per block/wave

    float v[64];

    // ---- load: lane owns n = lane*64 + j, j = 0..63 (16 x float4) ----
    {
        const float4* src = reinterpret_cast<const float4*>(x + row * DIM + lane * 64);
#pragma unroll
        for (int q = 0; q < 16; ++q) {
            float4 t = src[q];
            v[4 * q + 0] = t.x;
            v[4 * q + 1] = t.y;
            v[4 * q + 2] = t.z;
            v[4 * q + 3] = t.w;
        }
    }

    // ---- phase 1: butterflies on bits 0..5 (register index j) ----
#pragma unroll
    for (int h = 1; h < 64; h <<= 1) {
#pragma unroll
        for (int i = 0; i < 64; i += 2 * h) {
#pragma unroll
            for (int k = 0; k < h; ++k) {
                float a = v[i + k];
                float b = v[i + k + h];
                v[i + k]     = a + b;
                v[i + k + h] = a - b;
            }
        }
    }

    // ---- LDS transpose: write value n = lane*64+j at buf[lane*PITCH + j] ----
    {
        float* wp = buf + lane * PITCH;
#pragma unroll
        for (int q = 0; q < 16; ++q) {
            float4 t;
            t.x = v[4 * q + 0];
            t.y = v[4 * q + 1];
            t.z = v[4 * q + 2];
            t.w = v[4 * q + 3];
            reinterpret_cast<float4*>(wp)[q] = t;
        }
    }
    __syncthreads();  // single wave per block: effectively just the lgkm drain

    // read transposed: register m now holds n = m*64 + lane
#pragma unroll
    for (int m = 0; m < 64; ++m) {
        v[m] = buf[m * PITCH + lane];
    }

    // ---- phase 2: butterflies on bits 6..11 (register index m) ----
#pragma unroll
    for (int h = 1; h < 64; h <<= 1) {
#pragma unroll
        for (int i = 0; i < 64; i += 2 * h) {
#pragma unroll
            for (int k = 0; k < h; ++k) {
                float a = v[i + k];
                float b = v[i + k + h];
                v[i + k]     = a + b;
                v[i + k + h] = a - b;
            }
        }
    }

    // ---- scale + store: value m sits at n = m*64 + lane (coalesced per m) ----
    const float scale = 0x1p-39f;  // 2^-(L(L+1)/4), L=12
    float* dst = y + row * DIM + lane;
#pragma unroll
    for (int m = 0; m < 64; ++m) {
        dst[m * 64] = v[m] * scale;
    }
}

extern "C" void kernel_launch(void* const* d_in, const int* in_sizes, int n_in,
                              void* d_out, int out_size, void* d_ws, size_t ws_size,
                              hipStream_t stream) {
    const float* x = (const float*)d_in[0];
    float* y = (float*)d_out;
    const int nrows = in_sizes[0] / DIM;  // 8192
    fwht4096_kernel<<<nrows, 64, 0, stream>>>(x, y);
}